// Round 2
// baseline (49555.084 us; speedup 1.0000x reference)
//
#include <hip/hip_runtime.h>
#include <math.h>

// EchoStateNetwork: B=32, S=4096, I=64, R=1024, O=8, fp32.
// 8 groups x 32 WGs; each group advances 4 chains. Each WG holds
// 32 rows x 1024 cols of W_res in VGPRs (64 f32/thread -> no spill).
// Thread (wave w = rowgroup, lane l = colblock): rows 4w..4w+3,
// cols {4l + 256s + j}. Dot partials reduced within-wave by paired
// butterfly. Group barrier via agent-scope atomic counter.

#define NS 4096
#define NI 64
#define NR 1024
#define NO 8
#define NB 32
#define NGRP 8
#define GPP 32      // WGs per group
#define CPG 4       // chains per group
#define WROWS 32    // W_res rows per WG
#define NT 512

__global__ void init_cnt_kernel(unsigned int* cnt) {
  cnt[threadIdx.x] = 0u;   // zero 4 KB of counters
}

__global__ __launch_bounds__(NT, 1) void esn_scan(
    const float* __restrict__ x, const float* __restrict__ Win,
    const float* __restrict__ Wres, const float* __restrict__ Wout,
    float* __restrict__ out, unsigned int* __restrict__ cnt,
    float* __restrict__ rbuf, float* __restrict__ pbuf)
{
  const int wg  = blockIdx.x;
  const int g   = wg & 7;    // group (stride-8 -> same XCD heuristic)
  const int m   = wg >> 3;   // member 0..31
  const int tid = threadIdx.x;
  const int w   = tid >> 6;  // wave 0..7 = rowgroup
  const int l   = tid & 63;  // lane = colblock

  __shared__ float r_lds[CPG][NR];          // r_{t-1} for 4 chains
  __shared__ float x_lds[2][CPG][NI + 1];   // [parity][chain][i]
  __shared__ float win_s[WROWS][NI + 1];    // W_in rows slice
  __shared__ float woutr_s[NO][WROWS + 1];  // W_out r-part own rows
  __shared__ float woutx_s[NO][NI];         // W_out x-part
  __shared__ float rv_s[WROWS][CPG];        // new r values (for W_out partials)

  // ---- startup: weights into registers / LDS ----
  float4 wv[4][4];  // [r][s]: W_res[32m+4w+r][4l+256s .. +4]
  {
    const int grow0 = 32 * m + 4 * w;
    #pragma unroll
    for (int r = 0; r < 4; ++r)
      #pragma unroll
      for (int s = 0; s < 4; ++s)
        wv[r][s] = *(const float4*)&Wres[(size_t)(grow0 + r) * NR + 4 * l + 256 * s];
  }
  for (int idx = tid; idx < WROWS * NI; idx += NT) {
    int rr = idx >> 6, ii = idx & 63;
    win_s[rr][ii] = Win[(32 * m + rr) * NI + ii];
  }
  for (int idx = tid; idx < NO * WROWS; idx += NT) {
    int o = idx >> 5, lr = idx & 31;
    woutr_s[o][lr] = Wout[o * (NI + NR) + NI + 32 * m + lr];
  }
  for (int idx = tid; idx < NO * NI; idx += NT) {
    int o = idx >> 6, ii = idx & 63;
    woutx_s[o][ii] = Wout[o * (NI + NR) + ii];
  }
  __syncthreads();

  unsigned int* mycnt = cnt + g * 64;  // 256 B apart per group

  for (int t = 0; t < NS; ++t) {
    const int par = t & 1, pprev = par ^ 1;

    // ---- Phase L: r_{t-1} -> LDS, x_t -> LDS ----
    if (t > 0) {
      const int c = tid >> 7, off = (tid & 127) * 4;
      const float* rp = rbuf + (size_t)pprev * NB * NR + (size_t)(4 * g + c) * NR;
      float4 a = *(const float4*)(rp + off);
      float4 b = *(const float4*)(rp + off + 512);
      *(float4*)&r_lds[c][off] = a;
      *(float4*)&r_lds[c][off + 512] = b;
    } else {
      for (int idx = tid; idx < CPG * NR; idx += NT) ((float*)r_lds)[idx] = 0.f;
    }
    if (tid < 256) {
      const int c = tid >> 6, ii = tid & 63;
      x_lds[par][c][ii] = x[((size_t)(4 * g + c) * NS + t) * NI + ii];
    }
    // ---- rotating reducer: finalize out[., t-1, .] ----
    if (t > 0 && m == ((t - 1) & 31) && w == 6 && l < 32) {
      const int c = l >> 3, o = l & 7, b = 4 * g + c;
      const float* pb = pbuf + (size_t)pprev * NB * GPP * NO + (size_t)b * GPP * NO + o;
      float s = 0.f;
      #pragma unroll
      for (int mm = 0; mm < GPP; ++mm) s += pb[mm * NO];
      #pragma unroll
      for (int ii = 0; ii < NI; ++ii)
        s = fmaf(woutx_s[o][ii], x_lds[pprev][c][ii], s);
      out[((size_t)b * NS + (t - 1)) * NO + o] = s;
    }
    __syncthreads();

    // ---- dot: acc[r][c] over this thread's 16 cols ----
    float acc[4][4];
    #pragma unroll
    for (int r = 0; r < 4; ++r)
      #pragma unroll
      for (int c = 0; c < 4; ++c) acc[r][c] = 0.f;
    #pragma unroll
    for (int s = 0; s < 4; ++s) {
      float4 f[4];
      #pragma unroll
      for (int c = 0; c < 4; ++c)
        f[c] = *(const float4*)&r_lds[c][4 * l + 256 * s];
      #pragma unroll
      for (int r = 0; r < 4; ++r) {
        #pragma unroll
        for (int c = 0; c < 4; ++c) {
          acc[r][c] = fmaf(wv[r][s].x, f[c].x, acc[r][c]);
          acc[r][c] = fmaf(wv[r][s].y, f[c].y, acc[r][c]);
          acc[r][c] = fmaf(wv[r][s].z, f[c].z, acc[r][c]);
          acc[r][c] = fmaf(wv[r][s].w, f[c].w, acc[r][c]);
        }
      }
    }

    // ---- paired butterfly: 16 sums across 64 lanes ----
    // final: lane holds total for accum k = (l & 15), k = 4*r + c
    float v[16];
    #pragma unroll
    for (int k = 0; k < 16; ++k) v[k] = acc[k >> 2][k & 3];
    #pragma unroll
    for (int lev = 0; lev < 4; ++lev) {
      const int d = 1 << lev;
      const int n = 16 >> lev;
      #pragma unroll
      for (int i = 0; i < n / 2; ++i) {
        float a  = v[2 * i]     + __shfl_xor(v[2 * i],     d);
        float bb = v[2 * i + 1] + __shfl_xor(v[2 * i + 1], d);
        v[i] = (l & d) ? bb : a;
      }
    }
    float dsum = v[0];
    dsum += __shfl_xor(dsum, 16);
    dsum += __shfl_xor(dsum, 32);

    // ---- finalize: pin + tanh + store ----
    if (l < 16) {
      const int r = l >> 2, c = l & 3;
      const int lrow = 4 * w + r;
      const int grow = 32 * m + lrow;
      float pin = 0.f;
      #pragma unroll
      for (int ii = 0; ii < NI; ++ii)
        pin = fmaf(win_s[lrow][ii], x_lds[par][c][ii], pin);
      float rv = tanhf(dsum + pin);
      rbuf[(size_t)par * NB * NR + (size_t)(4 * g + c) * NR + grow] = rv;
      rv_s[lrow][c] = rv;
    }
    __syncthreads();

    // ---- W_out partials for this WG's 32 rows ----
    if (w == 7 && l < 32) {
      const int c = l >> 3, o = l & 7;
      float s2 = 0.f;
      #pragma unroll
      for (int lr = 0; lr < WROWS; ++lr)
        s2 = fmaf(rv_s[lr][c], woutr_s[o][lr], s2);
      pbuf[(size_t)par * NB * GPP * NO + ((size_t)(4 * g + c) * GPP + m) * NO + o] = s2;
    }

    // ---- group barrier (32 WGs) ----
    __syncthreads();  // drains vmcnt: all stores issued
    if (tid == 0) {
      __hip_atomic_fetch_add(mycnt, 1u, __ATOMIC_RELEASE, __HIP_MEMORY_SCOPE_AGENT);
      const unsigned int target = (unsigned int)(GPP * (t + 1));
      while (__hip_atomic_load(mycnt, __ATOMIC_ACQUIRE, __HIP_MEMORY_SCOPE_AGENT) < target) { }
    }
    __syncthreads();
  }

  // ---- final reduction for t = NS-1 (member 31) ----
  if (m == 31 && w == 6 && l < 32) {
    const int c = l >> 3, o = l & 7, b = 4 * g + c;
    const int fpar = (NS - 1) & 1;
    const float* pb = pbuf + (size_t)fpar * NB * GPP * NO + (size_t)b * GPP * NO + o;
    float s = 0.f;
    #pragma unroll
    for (int mm = 0; mm < GPP; ++mm) s += pb[mm * NO];
    #pragma unroll
    for (int ii = 0; ii < NI; ++ii)
      s = fmaf(woutx_s[o][ii], x_lds[fpar][c][ii], s);
    out[((size_t)b * NS + (NS - 1)) * NO + o] = s;
  }
}

extern "C" void kernel_launch(void* const* d_in, const int* in_sizes, int n_in,
                              void* d_out, int out_size, void* d_ws, size_t ws_size,
                              hipStream_t stream) {
  const float* x    = (const float*)d_in[0];
  const float* Win  = (const float*)d_in[1];
  const float* Wres = (const float*)d_in[2];
  const float* Wout = (const float*)d_in[3];
  float* out = (float*)d_out;

  char* ws = (char*)d_ws;
  unsigned int* cnt = (unsigned int*)ws;                 // 4 KB (8 groups x 256 B)
  float* rbuf = (float*)(ws + 4096);                     // 2*32*1024*4 = 256 KB
  float* pbuf = (float*)(ws + 4096 + 2 * NB * NR * 4);   // 2*32*32*8*4 = 64 KB

  hipLaunchKernelGGL(init_cnt_kernel, dim3(1), dim3(1024), 0, stream, cnt);
  hipLaunchKernelGGL(esn_scan, dim3(256), dim3(NT), 0, stream,
                     x, Win, Wres, Wout, out, cnt, rbuf, pbuf);
}

// Round 3
// 18237.366 us; speedup vs baseline: 2.7172x; 2.7172x over previous
//
#include <hip/hip_runtime.h>
#include <math.h>

// EchoStateNetwork: B=32, S=4096, I=64, R=1024, O=8, fp32.
// 8 groups x 32 WGs; each group advances 4 chains. Each WG holds
// 32 rows x 1024 cols of W_res in VGPRs (64 f32/thread).
// Occupancy forced to 1 WG/CU (LDS pad > 80KB + amdgpu_waves_per_eu(2,2))
// so the register allocator gets a 256-VGPR budget -> no spill.
// Cross-WG exchange uses RELAXED agent-scope atomics only (sc1 accesses,
// no buffer_inv/wbl2 cache maintenance); ordering via the vmcnt(0) drain
// implied by __syncthreads() before the counter increment.

#define NS 4096
#define NI 64
#define NR 1024
#define NO 8
#define NB 32
#define NGRP 8
#define GPP 32      // WGs per group
#define CPG 4       // chains per group
#define WROWS 32    // W_res rows per WG
#define NT 512

#define ATLF(p)   __hip_atomic_load((p), __ATOMIC_RELAXED, __HIP_MEMORY_SCOPE_AGENT)
#define ATSF(p,v) __hip_atomic_store((p), (v), __ATOMIC_RELAXED, __HIP_MEMORY_SCOPE_AGENT)
#define ATLU(p)   __hip_atomic_load((p), __ATOMIC_RELAXED, __HIP_MEMORY_SCOPE_AGENT)

__global__ void init_cnt_kernel(unsigned int* cnt) {
  cnt[threadIdx.x] = 0u;   // zero 4 KB of counters
}

__global__ __launch_bounds__(NT)
__attribute__((amdgpu_waves_per_eu(2, 2)))
void esn_scan(const float* __restrict__ x, const float* __restrict__ Win,
              const float* __restrict__ Wres, const float* __restrict__ Wout,
              float* __restrict__ out, unsigned int* __restrict__ cnt,
              float* __restrict__ rbuf, float* __restrict__ pbuf)
{
  const int wg  = blockIdx.x;
  const int g   = wg & 7;    // group (stride-8 -> same-XCD heuristic)
  const int m   = wg >> 3;   // member 0..31
  const int tid = threadIdx.x;
  const int w   = tid >> 6;  // wave 0..7 = rowgroup
  const int l   = tid & 63;  // lane = colblock

  __shared__ float r_lds[CPG][NR];          // r_{t-1} for 4 chains
  __shared__ float x_lds[2][CPG][NI + 1];   // [parity][chain][i]
  __shared__ float win_s[WROWS][NI + 1];    // W_in rows slice
  __shared__ float woutr_s[NO][WROWS + 1];  // W_out r-part own rows
  __shared__ float woutx_s[NO][NI];         // W_out x-part
  __shared__ float rv_s[WROWS][CPG];        // new r values
  __shared__ float pad_lds[14336];          // 56 KB occupancy shaping -> 1 WG/CU

  // keep pad_lds alive (condition is never true for this input, but the
  // compiler cannot prove it)
  if (x[0] == 1234.5678f) pad_lds[tid] = Win[tid & 63];

  // ---- startup: weights into registers / LDS ----
  float4 wv[4][4];  // [r][s]: W_res[32m+4w+r][4l+256s .. +4]
  {
    const int grow0 = 32 * m + 4 * w;
    #pragma unroll
    for (int r = 0; r < 4; ++r)
      #pragma unroll
      for (int s = 0; s < 4; ++s)
        wv[r][s] = *(const float4*)&Wres[(size_t)(grow0 + r) * NR + 4 * l + 256 * s];
  }
  for (int idx = tid; idx < WROWS * NI; idx += NT) {
    int rr = idx >> 6, ii = idx & 63;
    win_s[rr][ii] = Win[(32 * m + rr) * NI + ii];
  }
  for (int idx = tid; idx < NO * WROWS; idx += NT) {
    int o = idx >> 5, lr = idx & 31;
    woutr_s[o][lr] = Wout[o * (NI + NR) + NI + 32 * m + lr];
  }
  for (int idx = tid; idx < NO * NI; idx += NT) {
    int o = idx >> 6, ii = idx & 63;
    woutx_s[o][ii] = Wout[o * (NI + NR) + ii];
  }
  __syncthreads();

  unsigned int* mycnt = cnt + g * 64;  // 256 B apart per group

  for (int t = 0; t < NS; ++t) {
    const int par = t & 1, pprev = par ^ 1;

    // ---- Phase L: r_{t-1} -> LDS (relaxed agent loads), x_t -> LDS ----
    if (t > 0) {
      const float* rp = rbuf + (size_t)pprev * NB * NR + (size_t)(4 * g) * NR;
      float tv[8];
      #pragma unroll
      for (int j = 0; j < 8; ++j) tv[j] = ATLF(rp + tid + 512 * j);
      #pragma unroll
      for (int j = 0; j < 8; ++j) ((float*)r_lds)[tid + 512 * j] = tv[j];
    } else {
      for (int idx = tid; idx < CPG * NR; idx += NT) ((float*)r_lds)[idx] = 0.f;
    }
    if (tid < 256) {
      const int c = tid >> 6, ii = tid & 63;
      x_lds[par][c][ii] = x[((size_t)(4 * g + c) * NS + t) * NI + ii];
    }
    // ---- rotating reducer: finalize out[., t-1, .] ----
    if (t > 0 && m == ((t - 1) & 31) && w == 6 && l < 32) {
      const int c = l >> 3, o = l & 7, b = 4 * g + c;
      const float* pb = pbuf + (size_t)pprev * NB * GPP * NO + (size_t)b * GPP * NO + o;
      float s = 0.f;
      #pragma unroll
      for (int mm = 0; mm < GPP; ++mm) s += ATLF(pb + mm * NO);
      #pragma unroll
      for (int ii = 0; ii < NI; ++ii)
        s = fmaf(woutx_s[o][ii], x_lds[pprev][c][ii], s);
      out[((size_t)b * NS + (t - 1)) * NO + o] = s;
    }
    __syncthreads();

    // ---- dot: acc[r][c] over this thread's 16 cols ----
    float acc[4][4];
    #pragma unroll
    for (int r = 0; r < 4; ++r)
      #pragma unroll
      for (int c = 0; c < 4; ++c) acc[r][c] = 0.f;
    #pragma unroll
    for (int s = 0; s < 4; ++s) {
      float4 f[4];
      #pragma unroll
      for (int c = 0; c < 4; ++c)
        f[c] = *(const float4*)&r_lds[c][4 * l + 256 * s];
      #pragma unroll
      for (int r = 0; r < 4; ++r) {
        #pragma unroll
        for (int c = 0; c < 4; ++c) {
          acc[r][c] = fmaf(wv[r][s].x, f[c].x, acc[r][c]);
          acc[r][c] = fmaf(wv[r][s].y, f[c].y, acc[r][c]);
          acc[r][c] = fmaf(wv[r][s].z, f[c].z, acc[r][c]);
          acc[r][c] = fmaf(wv[r][s].w, f[c].w, acc[r][c]);
        }
      }
    }

    // ---- paired butterfly: 16 sums across 64 lanes ----
    // final: lane k = (l & 15) holds total for accum k = 4*r + c
    float v[16];
    #pragma unroll
    for (int k = 0; k < 16; ++k) v[k] = acc[k >> 2][k & 3];
    #pragma unroll
    for (int lev = 0; lev < 4; ++lev) {
      const int d = 1 << lev;
      const int n = 16 >> lev;
      #pragma unroll
      for (int i = 0; i < n / 2; ++i) {
        float a  = v[2 * i]     + __shfl_xor(v[2 * i],     d);
        float bb = v[2 * i + 1] + __shfl_xor(v[2 * i + 1], d);
        v[i] = (l & d) ? bb : a;
      }
    }
    float dsum = v[0];
    dsum += __shfl_xor(dsum, 16);
    dsum += __shfl_xor(dsum, 32);

    // ---- finalize: pin + tanh + store (relaxed agent store) ----
    if (l < 16) {
      const int r = l >> 2, c = l & 3;
      const int lrow = 4 * w + r;
      const int grow = 32 * m + lrow;
      float pin = 0.f;
      #pragma unroll
      for (int ii = 0; ii < NI; ++ii)
        pin = fmaf(win_s[lrow][ii], x_lds[par][c][ii], pin);
      float rv = tanhf(dsum + pin);
      ATSF(rbuf + (size_t)par * NB * NR + (size_t)(4 * g + c) * NR + grow, rv);
      rv_s[lrow][c] = rv;
    }
    __syncthreads();

    // ---- W_out partials for this WG's 32 rows ----
    if (w == 7 && l < 32) {
      const int c = l >> 3, o = l & 7;
      float s2 = 0.f;
      #pragma unroll
      for (int lr = 0; lr < WROWS; ++lr)
        s2 = fmaf(rv_s[lr][c], woutr_s[o][lr], s2);
      ATSF(pbuf + (size_t)par * NB * GPP * NO + ((size_t)(4 * g + c) * GPP + m) * NO + o, s2);
    }

    // ---- group barrier (32 WGs), relaxed atomics only ----
    // __syncthreads() drains vmcnt(0): all sc1 stores above are at the
    // coherence point before tid 0 increments the counter.
    __syncthreads();
    if (tid == 0) {
      __hip_atomic_fetch_add(mycnt, 1u, __ATOMIC_RELAXED, __HIP_MEMORY_SCOPE_AGENT);
      const unsigned int target = (unsigned int)(GPP * (t + 1));
      while (ATLU(mycnt) < target) { }
    }
    __syncthreads();
  }

  // ---- final reduction for t = NS-1 (member 31) ----
  if (m == 31 && w == 6 && l < 32) {
    const int c = l >> 3, o = l & 7, b = 4 * g + c;
    const int fpar = (NS - 1) & 1;
    const float* pb = pbuf + (size_t)fpar * NB * GPP * NO + (size_t)b * GPP * NO + o;
    float s = 0.f;
    #pragma unroll
    for (int mm = 0; mm < GPP; ++mm) s += ATLF(pb + mm * NO);
    #pragma unroll
    for (int ii = 0; ii < NI; ++ii)
      s = fmaf(woutx_s[o][ii], x_lds[fpar][c][ii], s);
    out[((size_t)b * NS + (NS - 1)) * NO + o] = s;
  }
}

extern "C" void kernel_launch(void* const* d_in, const int* in_sizes, int n_in,
                              void* d_out, int out_size, void* d_ws, size_t ws_size,
                              hipStream_t stream) {
  const float* x    = (const float*)d_in[0];
  const float* Win  = (const float*)d_in[1];
  const float* Wres = (const float*)d_in[2];
  const float* Wout = (const float*)d_in[3];
  float* out = (float*)d_out;

  char* ws = (char*)d_ws;
  unsigned int* cnt = (unsigned int*)ws;                 // 4 KB (8 groups x 256 B)
  float* rbuf = (float*)(ws + 4096);                     // 2*32*1024*4 = 256 KB
  float* pbuf = (float*)(ws + 4096 + 2 * NB * NR * 4);   // 2*32*32*8*4 = 64 KB

  hipLaunchKernelGGL(init_cnt_kernel, dim3(1), dim3(1024), 0, stream, cnt);
  hipLaunchKernelGGL(esn_scan, dim3(256), dim3(NT), 0, stream,
                     x, Win, Wres, Wout, out, cnt, rbuf, pbuf);
}

// Round 5
// 15252.415 us; speedup vs baseline: 3.2490x; 1.1957x over previous
//
#include <hip/hip_runtime.h>
#include <math.h>

// EchoStateNetwork: B=32, S=4096, I=64, R=1024, O=8, fp32.
// 8 groups x 32 WGs by blockIdx (placement-independent correctness);
// each group advances 4 chains. Each WG: 32 rows x 1024 cols of W_res in
// VGPRs (64 f32/thread; amdgpu_waves_per_eu(2,2) -> 256-reg budget, no
// spill). Cross-WG exchange: RELAXED agent-scope atomics only (proven in
// round 3); ordering via the vmcnt(0) drain of __syncthreads before the
// arrival add. Arrive-early/wait-late barrier with shadow work:
// x[t+1] prefetch + rotating LOCAL output reduction (every WG has the
// full r_{t-1} in LDS, so out[.,t-1,.] needs no cross-WG partials).

#define NS 4096
#define NI 64
#define NR 1024
#define NO 8
#define NB 32
#define NGRP 8
#define GPP 32      // WGs per group
#define CPG 4       // chains per group
#define WROWS 32    // W_res rows per WG
#define NT 512
#define WOC (NI + NR + 1)   // padded W_out row stride in LDS

#define ATLF(p)   __hip_atomic_load((p), __ATOMIC_RELAXED, __HIP_MEMORY_SCOPE_AGENT)
#define ATSF(p,v) __hip_atomic_store((p), (v), __ATOMIC_RELAXED, __HIP_MEMORY_SCOPE_AGENT)
#define ATLU(p)   __hip_atomic_load((p), __ATOMIC_RELAXED, __HIP_MEMORY_SCOPE_AGENT)

__global__ void init_cnt_kernel(unsigned int* cnt) {
  cnt[threadIdx.x] = 0u;   // zero 4 KB of barrier counters
}

__global__ __launch_bounds__(NT)
__attribute__((amdgpu_waves_per_eu(2, 2)))
void esn_scan(const float* __restrict__ x, const float* __restrict__ Win,
              const float* __restrict__ Wres, const float* __restrict__ Wout,
              float* __restrict__ out, unsigned int* __restrict__ cnt,
              float* __restrict__ rbuf)
{
  extern __shared__ float dynpad[];  // 64 KB occupancy shaping (dispatch-reserved)
  const int wg  = blockIdx.x;
  const int g   = wg & 7;    // group
  const int m   = wg >> 3;   // member 0..31
  const int tid = threadIdx.x;
  const int w   = tid >> 6;  // wave 0..7
  const int l   = tid & 63;  // lane

  __shared__ float r_lds[CPG][NR];         // 16 KB: full r_{t-1}, 4 chains
  __shared__ float x_lds[3][CPG][NI + 1];  // mod-3 ring: x[t-1], x[t], x[t+1]
  __shared__ float win_s[WROWS][NI + 1];   // 8.1 KB
  __shared__ float wout_s[NO][WOC];        // 34.8 KB: FULL W_out (x part + r part)

  // never-true guard keeps dynpad referenced
  if (x[0] == 1234.5678f) { dynpad[tid] = 1.f; out[tid] = dynpad[tid ^ 1]; }

  // ---- startup: weights into registers / LDS ----
  float4 wv[4][4];  // [r][s]: W_res[32m+4w+r][4l+256s .. +4]
  {
    const int grow0 = 32 * m + 4 * w;
    #pragma unroll
    for (int r = 0; r < 4; ++r)
      #pragma unroll
      for (int s = 0; s < 4; ++s)
        wv[r][s] = *(const float4*)&Wres[(size_t)(grow0 + r) * NR + 4 * l + 256 * s];
  }
  for (int idx = tid; idx < WROWS * NI; idx += NT) {
    int rr = idx >> 6, ii = idx & 63;
    win_s[rr][ii] = Win[(32 * m + rr) * NI + ii];
  }
  for (int idx = tid; idx < NO * (NI + NR); idx += NT) {
    int o = idx / (NI + NR), f = idx % (NI + NR);
    wout_s[o][f] = Wout[o * (NI + NR) + f];
  }
  if (tid < 256) {  // x[0] into ring slot 0
    const int c = tid >> 6, ii = tid & 63;
    x_lds[0][c][ii] = x[(size_t)(4 * g + c) * NS * NI + ii];
  }
  __syncthreads();

  unsigned int* bcp = cnt + g * 64;  // barrier counter (256 B apart per group)

  for (int t = 0; t < NS; ++t) {
    const int par = t & 1, pprev = par ^ 1;

    // ---- Phase L: gather r_{t-1} (relaxed agent loads -> LDS) ----
    if (t > 0) {
      const float* rp = rbuf + (size_t)pprev * NB * NR + (size_t)(4 * g) * NR;
      float tv[8];
      #pragma unroll
      for (int j = 0; j < 8; ++j) tv[j] = ATLF(rp + tid + 512 * j);
      #pragma unroll
      for (int j = 0; j < 8; ++j) ((float*)r_lds)[tid + 512 * j] = tv[j];
    } else {
      for (int idx = tid; idx < CPG * NR; idx += NT) ((float*)r_lds)[idx] = 0.f;
    }
    __syncthreads();

    // ---- dot: acc[r][c] over this thread's 16 cols ----
    float acc[4][4];
    #pragma unroll
    for (int r = 0; r < 4; ++r)
      #pragma unroll
      for (int c = 0; c < 4; ++c) acc[r][c] = 0.f;
    #pragma unroll
    for (int s = 0; s < 4; ++s) {
      float4 f[4];
      #pragma unroll
      for (int c = 0; c < 4; ++c)
        f[c] = *(const float4*)&r_lds[c][4 * l + 256 * s];
      #pragma unroll
      for (int r = 0; r < 4; ++r) {
        #pragma unroll
        for (int c = 0; c < 4; ++c) {
          acc[r][c] = fmaf(wv[r][s].x, f[c].x, acc[r][c]);
          acc[r][c] = fmaf(wv[r][s].y, f[c].y, acc[r][c]);
          acc[r][c] = fmaf(wv[r][s].z, f[c].z, acc[r][c]);
          acc[r][c] = fmaf(wv[r][s].w, f[c].w, acc[r][c]);
        }
      }
    }

    // ---- paired butterfly: 16 sums across 64 lanes ----
    float v[16];
    #pragma unroll
    for (int k = 0; k < 16; ++k) v[k] = acc[k >> 2][k & 3];
    #pragma unroll
    for (int lev = 0; lev < 4; ++lev) {
      const int d = 1 << lev;
      const int n = 16 >> lev;
      #pragma unroll
      for (int i = 0; i < n / 2; ++i) {
        float a  = v[2 * i]     + __shfl_xor(v[2 * i],     d);
        float bb = v[2 * i + 1] + __shfl_xor(v[2 * i + 1], d);
        v[i] = (l & d) ? bb : a;
      }
    }
    float dsum = v[0];
    dsum += __shfl_xor(dsum, 16);
    dsum += __shfl_xor(dsum, 32);

    // ---- finalize: pin + tanh + relaxed agent store ----
    if (l < 16) {
      const int r = l >> 2, c = l & 3;
      const int lrow = 4 * w + r;
      const int grow = 32 * m + lrow;
      float pin = 0.f;
      #pragma unroll
      for (int ii = 0; ii < NI; ++ii)
        pin = fmaf(win_s[lrow][ii], x_lds[t % 3][c][ii], pin);
      float rv = tanhf(dsum + pin);
      ATSF(rbuf + (size_t)par * NB * NR + (size_t)(4 * g + c) * NR + grow, rv);
    }

    // ---- arrive (early): all this WG's stores drained by the barrier ----
    __syncthreads();  // emits s_waitcnt vmcnt(0) per wave before s_barrier
    if (tid == 0)
      __hip_atomic_fetch_add(bcp, 1u, __ATOMIC_RELAXED, __HIP_MEMORY_SCOPE_AGENT);

    // ---- shadow work while the group converges ----
    // x[t+1] prefetch into ring slot (t+1)%3
    if (t + 1 < NS && tid < 256) {
      const int c = tid >> 6, ii = tid & 63;
      x_lds[(t + 1) % 3][c][ii] = x[((size_t)(4 * g + c) * NS + (t + 1)) * NI + ii];
    }
    // rotating reducer: out[., t-1, .] fully local (r_{t-1} is in r_lds)
    if (t > 0 && m == ((t - 1) & 31)) {
      const int grp = tid >> 4;   // 0..31 -> (c,o)
      const int j   = tid & 15;
      const int c   = grp >> 3, o = grp & 7;
      float s = 0.f;
      #pragma unroll
      for (int k = 0; k < 16; ++k) {
        const int fb = 64 * k + 4 * j;
        float4 rr = *(const float4*)&r_lds[c][fb];
        float4 ww = *(const float4*)&wout_s[o][NI + fb];
        s = fmaf(ww.x, rr.x, s); s = fmaf(ww.y, rr.y, s);
        s = fmaf(ww.z, rr.z, s); s = fmaf(ww.w, rr.w, s);
      }
      #pragma unroll
      for (int e = 0; e < 4; ++e)
        s = fmaf(wout_s[o][4 * j + e], x_lds[(t + 2) % 3][c][4 * j + e], s);
      s += __shfl_xor(s, 1); s += __shfl_xor(s, 2);
      s += __shfl_xor(s, 4); s += __shfl_xor(s, 8);
      if (j == 0) out[((size_t)(4 * g + c) * NS + (t - 1)) * NO + o] = s;
    }

    // ---- wait (late) ----
    if (tid == 0) {
      const unsigned target = (unsigned)(GPP * (t + 1));
      while (ATLU(bcp) < target) { }
    }
    __syncthreads();
  }

  // ---- final output row t = NS-1 (one WG per group; r_{NS-1} from rbuf) ----
  if (m == 31) {
    const int fpar = (NS - 1) & 1;
    const float* rp = rbuf + (size_t)fpar * NB * NR + (size_t)(4 * g) * NR;
    float tv[8];
    #pragma unroll
    for (int j = 0; j < 8; ++j) tv[j] = ATLF(rp + tid + 512 * j);
    #pragma unroll
    for (int j = 0; j < 8; ++j) ((float*)r_lds)[tid + 512 * j] = tv[j];
    __syncthreads();
    const int grp = tid >> 4;
    const int j   = tid & 15;
    const int c   = grp >> 3, o = grp & 7;
    float s = 0.f;
    #pragma unroll
    for (int k = 0; k < 16; ++k) {
      const int fb = 64 * k + 4 * j;
      float4 rr = *(const float4*)&r_lds[c][fb];
      float4 ww = *(const float4*)&wout_s[o][NI + fb];
      s = fmaf(ww.x, rr.x, s); s = fmaf(ww.y, rr.y, s);
      s = fmaf(ww.z, rr.z, s); s = fmaf(ww.w, rr.w, s);
    }
    #pragma unroll
    for (int e = 0; e < 4; ++e)
      s = fmaf(wout_s[o][4 * j + e], x_lds[(NS - 1) % 3][c][4 * j + e], s);
    s += __shfl_xor(s, 1); s += __shfl_xor(s, 2);
    s += __shfl_xor(s, 4); s += __shfl_xor(s, 8);
    if (j == 0) out[((size_t)(4 * g + c) * NS + (NS - 1)) * NO + o] = s;
  }
}

extern "C" void kernel_launch(void* const* d_in, const int* in_sizes, int n_in,
                              void* d_out, int out_size, void* d_ws, size_t ws_size,
                              hipStream_t stream) {
  const float* x    = (const float*)d_in[0];
  const float* Win  = (const float*)d_in[1];
  const float* Wres = (const float*)d_in[2];
  const float* Wout = (const float*)d_in[3];
  float* out = (float*)d_out;

  char* ws = (char*)d_ws;
  unsigned int* cnt = (unsigned int*)ws;      // 4 KB barrier counters
  float* rbuf = (float*)(ws + 4096);          // 2*32*1024*4 = 256 KB

  hipLaunchKernelGGL(init_cnt_kernel, dim3(1), dim3(1024), 0, stream, cnt);
  hipLaunchKernelGGL(esn_scan, dim3(256), dim3(NT), 64 * 1024, stream,
                     x, Win, Wres, Wout, out, cnt, rbuf);
}